// Round 13
// baseline (252.396 us; speedup 1.0000x reference)
//
#include <hip/hip_runtime.h>
#include <hip/hip_bf16.h>

typedef __attribute__((ext_vector_type(4))) float f32x4;
typedef __attribute__((ext_vector_type(8))) short s16x8;

#define MFMA16(a,b,c) __builtin_amdgcn_mfma_f32_16x16x32_bf16(a,b,c,0,0,0)

__device__ __forceinline__ unsigned short f2bf(float f){
  __hip_bfloat16 h = __float2bfloat16(f);
  return *reinterpret_cast<unsigned short*>(&h);
}

__device__ __forceinline__ s16x8 cvt8(f32x4 a, f32x4 b){
  s16x8 t;
  t[0]=(short)f2bf(a[0]); t[1]=(short)f2bf(a[1]);
  t[2]=(short)f2bf(a[2]); t[3]=(short)f2bf(a[3]);
  t[4]=(short)f2bf(b[0]); t[5]=(short)f2bf(b[1]);
  t[6]=(short)f2bf(b[2]); t[7]=(short)f2bf(b[3]);
  return t;
}

__device__ __forceinline__ void gload_lds16(const unsigned short* g, unsigned short* l){
  __builtin_amdgcn_global_load_lds(
      (const __attribute__((address_space(1))) unsigned int*)(const void*)g,
      (__attribute__((address_space(3))) unsigned int*)(void*)l,
      16, 0, 0);
}

// ---------------- fused x->bf16 cast + weight prep (R10-proven) ------------
__global__ void k_prep2(const float* __restrict__ x,
                        const float* __restrict__ qkv_w,   // (512,1536)
                        const float* __restrict__ qkv_b,   // (1536)
                        const float* __restrict__ proj_w,  // (512,512)
                        const float* __restrict__ btab,    // (169,16)
                        unsigned short* __restrict__ xb,      // (50176,512) bf16
                        unsigned short* __restrict__ wqkv_t,  // (1536,512) bf16
                        unsigned short* __restrict__ wproj_t, // (512,512) bf16
                        float* __restrict__ bqkv_s,           // (1536) f32
                        float* __restrict__ bias_t)           // (16,64,64) f32
{
  if (blockIdx.x < 12544){
    const int i = blockIdx.x * 256 + threadIdx.x;
    const float* p = x + (size_t)i*8;
    f32x4 v0 = *(const f32x4*)p, v1 = *(const f32x4*)(p+4);
    *(s16x8*)(xb + (size_t)i*8) = cvt8(v0, v1);
    return;
  }
  const float scale = 0.17677669529663687f; // 32^-0.5
  int tid = (blockIdx.x - 12544) * 256 + threadIdx.x;
  int np  = 512 * 256;
  for (int i = tid; i < 1536*512; i += np){
    int c = i >> 9, k = i & 511;
    float w = qkv_w[k*1536 + c];
    if (c < 512) w *= scale;
    wqkv_t[i] = f2bf(w);
  }
  for (int i = tid; i < 512*512; i += np){
    int c = i >> 9, k = i & 511;
    wproj_t[i] = f2bf(proj_w[k*512 + c]);
  }
  for (int i = tid; i < 1536; i += np){
    float bv = qkv_b[i];
    if (i < 512) bv *= scale;
    bqkv_s[i] = bv;
  }
  for (int i = tid; i < 16*64*64; i += np){
    int hh = i >> 12, rc = i & 4095, row = rc >> 6, col = rc & 63;
    float v;
    if (col >= 49)      v = -1e30f;
    else if (row >= 49) v = 0.f;
    else {
      int qy = row/7, qx = row%7, ky = col/7, kx = col%7;
      v = btab[((qy-ky+6)*13 + (qx-kx+6))*16 + hh];
    }
    bias_t[i] = v;
  }
}

// ---------------- qkv GEMM: proj2 structure, N=1536 (R12-proven) -----------
__global__ __launch_bounds__(256) void k_qkv2(
    const unsigned short* __restrict__ xb,     // (50176,512) bf16
    const unsigned short* __restrict__ wqkv_t, // (1536,512) bf16 (q pre-scaled)
    const float* __restrict__ bqkv_s,          // (1536) f32 (q pre-scaled)
    unsigned short* __restrict__ qkvb)         // (50176,1536) bf16
{
  __shared__ unsigned short lds[16384];   // A:[0,8192) dbuf, B:[8192,16384) dbuf
  const int t    = threadIdx.x;
  const int lane = t & 63;
  const int wave = t >> 6;
  const int l16  = lane & 15;
  const int lg   = lane >> 4;
  const int wr   = wave >> 1;
  const int wc   = wave & 1;
  const f32x4 ZERO4 = {0.f, 0.f, 0.f, 0.f};

  const int bid  = blockIdx.x;
  const int xcd  = bid & 7;
  const int idx  = bid >> 3;
  const int nb   = idx % 12;
  const int mgrp = idx / 12;          // 0..48
  const int mb   = xcd*49 + mgrp;     // 0..391
  const int m0   = mb * 128;
  const int n0   = nb * 128;

  const int srow = t >> 2;            // 0..63
  const int scol = (t & 3) * 8;
  const unsigned short* asrc = xb     + (size_t)(m0 + srow)*512 + scol;
  const unsigned short* bsrc = wqkv_t + (size_t)(n0 + srow)*512 + scol;

  gload_lds16(asrc,          lds + wave*512);
  gload_lds16(asrc + 32768,  lds + 2048 + wave*512);
  gload_lds16(bsrc,          lds + 8192 + wave*512);
  gload_lds16(bsrc + 32768,  lds + 8192 + 2048 + wave*512);
  __syncthreads();

  f32x4 acc[4][4];
  #pragma unroll
  for (int rt=0;rt<4;++rt)
    #pragma unroll
    for (int ct=0;ct<4;++ct)
      acc[rt][ct] = ZERO4;

  #pragma unroll 2
  for (int ks = 0; ks < 16; ++ks){
    const int p = ks & 1;
    unsigned short* Ab = lds + p*4096;
    unsigned short* Bb = lds + 8192 + p*4096;

    if (ks < 15){
      const int q = (ks+1) & 1;
      const unsigned short* a2 = asrc + (ks+1)*32;
      const unsigned short* b2 = bsrc + (ks+1)*32;
      gload_lds16(a2,         lds + q*4096 + wave*512);
      gload_lds16(a2 + 32768, lds + q*4096 + 2048 + wave*512);
      gload_lds16(b2,         lds + 8192 + q*4096 + wave*512);
      gload_lds16(b2 + 32768, lds + 8192 + q*4096 + 2048 + wave*512);
    }

    s16x8 af[4], bf[4];
    #pragma unroll
    for (int rt=0;rt<4;++rt)
      af[rt] = *(const s16x8*)&Ab[(wr*64 + rt*16 + l16)*32 + lg*8];
    #pragma unroll
    for (int ct=0;ct<4;++ct)
      bf[ct] = *(const s16x8*)&Bb[(wc*64 + ct*16 + l16)*32 + lg*8];

    #pragma unroll
    for (int rt=0;rt<4;++rt)
      #pragma unroll
      for (int ct=0;ct<4;++ct)
        acc[rt][ct] = MFMA16(af[rt], bf[ct], acc[rt][ct]);

    __syncthreads();
  }

  #pragma unroll
  for (int ct=0;ct<4;++ct){
    const int col = n0 + wc*64 + ct*16 + l16;
    const float bv = bqkv_s[col];
    #pragma unroll
    for (int rt=0;rt<4;++rt){
      const int row = m0 + wr*64 + rt*16 + lg*4;
      #pragma unroll
      for (int r=0;r<4;++r)
        qkvb[(size_t)(row+r)*1536 + col] = f2bf(acc[rt][ct][r] + bv);
    }
  }
}

// ---------------- attention kernel v3: P streamed through half-buffer ------
// grid 4096 (XCD-swizzled); block 256 = 4 waves, wave <-> one head.
// Per-wave LDS: ph[64][40]=2560 + vT[64][32]=2048 shorts = 9216 B;
// block 36864 B -> 4 blocks/CU. PV kt=0 on P cols 0..31, then the buffer is
// overwritten with cols 32..63 (still live in sacc) for PV kt=1.
__global__ __launch_bounds__(256, 4) void k_attn3(
    const unsigned short* __restrict__ qkvb,  // (50176,1536) bf16
    const float* __restrict__ bias_t,         // (16,64,64) f32, mask folded
    unsigned short* __restrict__ att)         // (1024,49,512) bf16
{
  __shared__ unsigned short lds[4*4608];
  const int lane = threadIdx.x & 63;
  const int wave = threadIdx.x >> 6;
  const int bid  = blockIdx.x;
  const int xcd  = bid & 7;
  const int g    = (bid >> 3) & 3;
  const int wblk = bid >> 5;
  const int b    = xcd + (wblk << 3);
  const int h    = (g << 2) | wave;
  const int l16  = lane & 15;
  const int lg   = lane >> 4;
  const f32x4 ZERO4 = {0.f, 0.f, 0.f, 0.f};

  unsigned short* ph = lds + wave*4608;   // [64][40] P-half / O restage
  unsigned short* vT = ph + 2560;         // [64][32] (token, d)
  const size_t wbase = (size_t)b * 49;

  // zero-seed vT rows 49..63 (DMA never writes them)
  for (int i = lane; i < 15*32; i += 64) vT[49*32 + i] = 0;

  // ---- stage V into LDS FIRST (max latency hiding under QK^T+softmax) ----
  {
    const int tokb = lane >> 2;          // 0..15
    const int sc   = (lane & 3) * 8;     // 16B segment
    #pragma unroll
    for (int i=0;i<4;++i){
      const int tok = i*16 + tokb;
      if (tok < 49)
        gload_lds16(qkvb + (wbase + tok)*1536 + 1024 + h*32 + sc,
                    vT + i*512);
    }
  }

  // ---- q,k fragments (one shot; rows >=49 zeroed) ----
  s16x8 aq[4], bk[4];
  #pragma unroll
  for (int rt=0;rt<4;++rt){
    const int n = rt*16 + l16;
    s16x8 z = {0,0,0,0,0,0,0,0};
    aq[rt] = z; bk[rt] = z;
    if (n < 49){
      const unsigned short* qp = qkvb + (wbase + n)*1536 + h*32 + lg*8;
      aq[rt] = *(const s16x8*)qp;
      bk[rt] = *(const s16x8*)(qp + 512);
    }
  }

  // ---- S = q @ k^T ----
  f32x4 sacc[4][4];
  #pragma unroll
  for (int rt=0;rt<4;++rt)
    #pragma unroll
    for (int ct=0;ct<4;++ct)
      sacc[rt][ct] = MFMA16(aq[rt], bk[ct], ZERO4);

  // ---- softmax: bias (mask folded), batched 16-row reductions ----
  const float* biash = bias_t + (h << 12);
  float pm[4][4];
  #pragma unroll
  for (int rt=0;rt<4;++rt){
    #pragma unroll
    for (int r=0;r<4;++r){
      const int row = rt*16 + lg*4 + r;
      const float* brow = biash + (row << 6) + l16;
      float s0 = sacc[rt][0][r] + brow[0];
      float s1 = sacc[rt][1][r] + brow[16];
      float s2 = sacc[rt][2][r] + brow[32];
      float s3 = sacc[rt][3][r] + brow[48];
      sacc[rt][0][r]=s0; sacc[rt][1][r]=s1; sacc[rt][2][r]=s2; sacc[rt][3][r]=s3;
      pm[rt][r] = fmaxf(fmaxf(s0,s1), fmaxf(s2,s3));
    }
  }
  #pragma unroll
  for (int d=1; d<16; d<<=1)
    #pragma unroll
    for (int rt=0;rt<4;++rt)
      #pragma unroll
      for (int r=0;r<4;++r)
        pm[rt][r] = fmaxf(pm[rt][r], __shfl_xor(pm[rt][r], d));

  float ps[4][4];
  #pragma unroll
  for (int rt=0;rt<4;++rt){
    #pragma unroll
    for (int r=0;r<4;++r){
      const float m = pm[rt][r];
      float e0 = __expf(sacc[rt][0][r]-m), e1 = __expf(sacc[rt][1][r]-m);
      float e2 = __expf(sacc[rt][2][r]-m), e3 = __expf(sacc[rt][3][r]-m);
      sacc[rt][0][r]=e0; sacc[rt][1][r]=e1; sacc[rt][2][r]=e2; sacc[rt][3][r]=e3;
      ps[rt][r] = e0+e1+e2+e3;
    }
  }
  #pragma unroll
  for (int d=1; d<16; d<<=1)
    #pragma unroll
    for (int rt=0;rt<4;++rt)
      #pragma unroll
      for (int r=0;r<4;++r)
        ps[rt][r] += __shfl_xor(ps[rt][r], d);
  #pragma unroll
  for (int rt=0;rt<4;++rt)
    #pragma unroll
    for (int r=0;r<4;++r)
      ps[rt][r] = 1.f / ps[rt][r];       // keep reciprocal for both halves

  // ---- write P cols 0..31 (ct 0,1) into ph ----
  #pragma unroll
  for (int rt=0;rt<4;++rt){
    #pragma unroll
    for (int r=0;r<4;++r){
      const int row = rt*16 + lg*4 + r;
      const float inv = ps[rt][r];
      ph[row*40 +      l16] = f2bf(sacc[rt][0][r]*inv);
      ph[row*40 + 16 + l16] = f2bf(sacc[rt][1][r]*inv);
    }
  }

  // V DMA + zero-seed + P writes must be visible before PV (wave-private)
  asm volatile("s_waitcnt vmcnt(0) lgkmcnt(0)" ::: "memory");
  __builtin_amdgcn_sched_barrier(0);

  f32x4 oacc[4][2];
  #pragma unroll
  for (int rt=0;rt<4;++rt)
    #pragma unroll
    for (int ct=0;ct<2;++ct)
      oacc[rt][ct] = ZERO4;

  // ---- PV kt=0 (P cols 0..31, V rows 0..31) ----
  {
    s16x8 ap[4], bv2[2];
    #pragma unroll
    for (int rt=0;rt<4;++rt)
      ap[rt] = *(const s16x8*)&ph[(rt*16+l16)*40 + lg*8];
    #pragma unroll
    for (int ct=0;ct<2;++ct){
      s16x8 fr;
      #pragma unroll
      for (int j=0;j<8;++j)
        fr[j] = (short)vT[(lg*8 + j)*32 + ct*16 + l16];
      bv2[ct] = fr;
    }
    #pragma unroll
    for (int rt=0;rt<4;++rt)
      #pragma unroll
      for (int ct=0;ct<2;++ct)
        oacc[rt][ct] = MFMA16(ap[rt], bv2[ct], oacc[rt][ct]);
  }

  // ---- overwrite ph with P cols 32..63 (ct 2,3) ----
  #pragma unroll
  for (int rt=0;rt<4;++rt){
    #pragma unroll
    for (int r=0;r<4;++r){
      const int row = rt*16 + lg*4 + r;
      const float inv = ps[rt][r];
      ph[row*40 +      l16] = f2bf(sacc[rt][2][r]*inv);
      ph[row*40 + 16 + l16] = f2bf(sacc[rt][3][r]*inv);
    }
  }

  // ---- PV kt=1 (P cols 32..63, V rows 32..63) ----
  {
    s16x8 ap[4], bv2[2];
    #pragma unroll
    for (int rt=0;rt<4;++rt)
      ap[rt] = *(const s16x8*)&ph[(rt*16+l16)*40 + lg*8];
    #pragma unroll
    for (int ct=0;ct<2;++ct){
      s16x8 fr;
      #pragma unroll
      for (int j=0;j<8;++j)
        fr[j] = (short)vT[(32 + lg*8 + j)*32 + ct*16 + l16];
      bv2[ct] = fr;
    }
    #pragma unroll
    for (int rt=0;rt<4;++rt)
      #pragma unroll
      for (int ct=0;ct<2;++ct)
        oacc[rt][ct] = MFMA16(ap[rt], bv2[ct], oacc[rt][ct]);
  }

  // ---- restage O through ph for coalesced bf16 stores ----
  #pragma unroll
  for (int rt=0;rt<4;++rt)
    #pragma unroll
    for (int ct=0;ct<2;++ct){
      const int row0 = rt*16 + lg*4;
      f32x4 vv = oacc[rt][ct];
      #pragma unroll
      for (int r=0;r<4;++r)
        ph[(row0+r)*40 + ct*16 + l16] = f2bf(vv[r]);
    }
  unsigned short* attb = att + (size_t)b*49*512 + h*32;
  for (int i = lane; i < 49*4; i += 64){
    const int row = i >> 2, seg = i & 3;
    *(s16x8*)&attb[(size_t)row*512 + seg*8] = *(const s16x8*)&ph[row*40 + seg*8];
  }
}

// ---------------- proj GEMM, m97-style (unchanged, proven) -----------------
__global__ __launch_bounds__(256) void k_proj2(
    const unsigned short* __restrict__ att,
    const unsigned short* __restrict__ wproj_t,
    const float* __restrict__ proj_b,
    float* __restrict__ out)
{
  __shared__ unsigned short lds[16384];
  const int t    = threadIdx.x;
  const int lane = t & 63;
  const int wave = t >> 6;
  const int l16  = lane & 15;
  const int lg   = lane >> 4;
  const int wr   = wave >> 1;
  const int wc   = wave & 1;
  const f32x4 ZERO4 = {0.f, 0.f, 0.f, 0.f};

  const int bid  = blockIdx.x;
  const int xcd  = bid & 7;
  const int idx  = bid >> 3;
  const int nb   = idx & 3;
  const int mgrp = idx >> 2;
  const int mb   = xcd*49 + mgrp;
  const int m0   = mb * 128;
  const int n0   = nb * 128;

  const int srow = t >> 2;
  const int scol = (t & 3) * 8;
  const unsigned short* asrc = att     + (size_t)(m0 + srow)*512 + scol;
  const unsigned short* bsrc = wproj_t + (size_t)(n0 + srow)*512 + scol;

  gload_lds16(asrc,          lds + wave*512);
  gload_lds16(asrc + 32768,  lds + 2048 + wave*512);
  gload_lds16(bsrc,          lds + 8192 + wave*512);
  gload_lds16(bsrc + 32768,  lds + 8192 + 2048 + wave*512);
  __syncthreads();

  f32x4 acc[4][4];
  #pragma unroll
  for (int rt=0;rt<4;++rt)
    #pragma unroll
    for (int ct=0;ct<4;++ct)
      acc[rt][ct] = ZERO4;

  #pragma unroll 2
  for (int ks = 0; ks < 16; ++ks){
    const int p = ks & 1;
    unsigned short* Ab = lds + p*4096;
    unsigned short* Bb = lds + 8192 + p*4096;

    if (ks < 15){
      const int q = (ks+1) & 1;
      const unsigned short* a2 = asrc + (ks+1)*32;
      const unsigned short* b2 = bsrc + (ks+1)*32;
      gload_lds16(a2,         lds + q*4096 + wave*512);
      gload_lds16(a2 + 32768, lds + q*4096 + 2048 + wave*512);
      gload_lds16(b2,         lds + 8192 + q*4096 + wave*512);
      gload_lds16(b2 + 32768, lds + 8192 + q*4096 + 2048 + wave*512);
    }

    s16x8 af[4], bf[4];
    #pragma unroll
    for (int rt=0;rt<4;++rt)
      af[rt] = *(const s16x8*)&Ab[(wr*64 + rt*16 + l16)*32 + lg*8];
    #pragma unroll
    for (int ct=0;ct<4;++ct)
      bf[ct] = *(const s16x8*)&Bb[(wc*64 + ct*16 + l16)*32 + lg*8];

    #pragma unroll
    for (int rt=0;rt<4;++rt)
      #pragma unroll
      for (int ct=0;ct<4;++ct)
        acc[rt][ct] = MFMA16(af[rt], bf[ct], acc[rt][ct]);

    __syncthreads();
  }

  #pragma unroll
  for (int ct=0;ct<4;++ct){
    const int col = n0 + wc*64 + ct*16 + l16;
    const float bv = proj_b[col];
    #pragma unroll
    for (int rt=0;rt<4;++rt){
      const int row = m0 + wr*64 + rt*16 + lg*4;
      #pragma unroll
      for (int r=0;r<4;++r)
        out[(size_t)(row+r)*512 + col] = acc[rt][ct][r] + bv;
    }
  }
}

// ================= R10 fused-attn kernel (fallback tier) ===================
__global__ __launch_bounds__(256, 3) void k_qkv_attn8(
    const unsigned short* __restrict__ xb,
    const unsigned short* __restrict__ wqkv_t,
    const float* __restrict__ bqkv_s,
    const float* __restrict__ bias_t,
    unsigned short* __restrict__ att)
{
  __shared__ unsigned short lds[4*5120 + 2*2048];
  const int lane = threadIdx.x & 63;
  const int wave = threadIdx.x >> 6;
  const int bid  = blockIdx.x;
  const int xcd  = bid & 7;
  const int g    = (bid >> 3) & 3;
  const int wblk = bid >> 5;
  const int b    = xcd + (wblk << 3);
  const int h    = (g << 2) | wave;
  const int l16  = lane & 15;
  const int lg   = lane >> 4;
  const f32x4 ZERO4 = {0.f, 0.f, 0.f, 0.f};

  unsigned short* q_lds  = lds + wave*5120;
  unsigned short* k_lds  = q_lds + 2560;
  unsigned short* p_lds  = q_lds;
  unsigned short* xstage = lds + 4*5120;

  for (int i = threadIdx.x; i < 2*15*32; i += 256){
    int bf = i / 480, rem = i % 480;
    xstage[bf*2048 + (49 + rem/32)*32 + (rem & 31)] = 0;
  }

  const unsigned short* xwin = xb + (size_t)b*49*512;
  const int srow = wave*16 + (lane>>2);
  const int cbase = h * 32;
  const unsigned short* xsrc = xwin + (size_t)srow*512 + (lane&3)*8;
  const unsigned short* bbase = wqkv_t + (size_t)(cbase + l16)*512 + lg*8;

  __syncthreads();
  if (srow < 49) gload_lds16(xsrc, xstage + wave*512);
  __syncthreads();

  f32x4 acc[3][4][2];
  #pragma unroll
  for (int a=0;a<3;++a)
    #pragma unroll
    for (int rt=0;rt<4;++rt)
      #pragma unroll
      for (int ct=0;ct<2;++ct)
        acc[a][rt][ct] = ZERO4;

  #pragma unroll 2
  for (int ks = 0; ks < 16; ++ks){
    const int p = ks & 1;
    s16x8 bfrag[6];
    #pragma unroll
    for (int wq=0; wq<3; ++wq)
      #pragma unroll
      for (int ct=0; ct<2; ++ct)
        bfrag[wq*2+ct] = *(const s16x8*)(bbase + wq*262144 + ct*8192 + ks*32);

    if (ks < 15 && srow < 49)
      gload_lds16(xsrc + (ks+1)*32, xstage + ((ks+1)&1)*2048 + wave*512);

    s16x8 afrag[4];
    #pragma unroll
    for (int rt=0; rt<4; ++rt)
      afrag[rt] = *(const s16x8*)&xstage[p*2048 + (rt*16 + l16)*32 + lg*8];

    #pragma unroll
    for (int wq=0;wq<3;++wq)
      #pragma unroll
      for (int rt=0;rt<4;++rt)
        #pragma unroll
        for (int ct=0;ct<2;++ct)
          acc[wq][rt][ct] = MFMA16(afrag[rt], bfrag[wq*2+ct], acc[wq][rt][ct]);

    __syncthreads();
  }

  uint2 vpk[4][2];
  #pragma unroll
  for (int wq=0; wq<3; ++wq){
    #pragma unroll
    for (int ct=0; ct<2; ++ct){
      const int c = wq*512 + cbase + ct*16 + l16;
      const float bv = bqkv_s[c];
      #pragma unroll
      for (int rt=0; rt<4; ++rt){
        f32x4 vv = acc[wq][rt][ct];
        const int row0 = rt*16 + lg*4;
        if (wq == 0){
          #pragma unroll
          for (int r=0;r<4;++r) q_lds[(row0+r)*40 + ct*16 + l16] = f2bf(vv[r]+bv);
        } else if (wq == 1){
          #pragma unroll
          for (int r=0;r<4;++r) k_lds[(row0+r)*40 + ct*16 + l16] = f2bf(vv[r]+bv);
        } else {
          uint2 pk;
          pk.x = (unsigned)f2bf(vv[0]+bv) | ((unsigned)f2bf(vv[1]+bv) << 16);
          pk.y = (unsigned)f2bf(vv[2]+bv) | ((unsigned)f2bf(vv[3]+bv) << 16);
          vpk[rt][ct] = pk;
        }
      }
    }
  }

  s16x8 aq[4], bk[4];
  #pragma unroll
  for (int t=0;t<4;++t){
    aq[t] = *(const s16x8*)&q_lds[(t*16+l16)*40 + lg*8];
    bk[t] = *(const s16x8*)&k_lds[(t*16+l16)*40 + lg*8];
  }
  f32x4 sacc[4][4];
  #pragma unroll
  for (int rt=0;rt<4;++rt)
    #pragma unroll
    for (int ct=0;ct<4;++ct)
      sacc[rt][ct] = MFMA16(aq[rt], bk[ct], ZERO4);

  const float* biash = bias_t + (h << 12);
  float pm[4][4];
  #pragma unroll
  for (int rt=0;rt<4;++rt){
    #pragma unroll
    for (int r=0;r<4;++r){
      const int row = rt*16 + lg*4 + r;
      const float* brow = biash + (row << 6) + l16;
      float s0 = sacc[rt][0][r] + brow[0];
      float s1 = sacc[rt][1][r] + brow[16];
      float s2 = sacc[rt][2][r] + brow[32];
      float s3 = sacc[rt][3][r] + brow[48];
      sacc[rt][0][r]=s0; sacc[rt][1][r]=s1; sacc[rt][2][r]=s2; sacc[rt][3][r]=s3;
      pm[rt][r] = fmaxf(fmaxf(s0,s1), fmaxf(s2,s3));
    }
  }
  #pragma unroll
  for (int d=1; d<16; d<<=1)
    #pragma unroll
    for (int rt=0;rt<4;++rt)
      #pragma unroll
      for (int r=0;r<4;++r)
        pm[rt][r] = fmaxf(pm[rt][r], __shfl_xor(pm[rt][r], d));

  float ps[4][4];
  #pragma unroll
  for (int rt=0;rt<4;++rt){
    #pragma unroll
    for (int r=0;r<4;++r){
      const float m = pm[rt][r];
      float e0 = __expf(sacc[rt][0][r]-m), e1 = __expf(sacc[rt][1][r]-m);
      float e2 = __expf(sacc[rt][2][r]-m), e3 = __expf(sacc[rt][3][r]-m);
      sacc[rt][0][r]=e0; sacc[rt][1][r]=e1; sacc[rt][2][r]=e2; sacc[rt][3][r]=e3;
      ps[rt][r] = e0+e1+e2+e3;
    }
  }
  #pragma unroll
  for (int d=1; d<16; d<<=1)
    #pragma unroll
    for (int rt=0;rt<4;++rt)
      #pragma unroll
      for (int r=0;r<4;++r)
        ps[rt][r] += __shfl_xor(ps[rt][r], d);

  #pragma unroll
  for (int rt=0;rt<4;++rt){
    #pragma unroll
    for (int r=0;r<4;++r){
      const int row = rt*16 + lg*4 + r;
      const float inv = 1.f / ps[rt][r];
      p_lds[row*72 +      l16] = f2bf(sacc[rt][0][r]*inv);
      p_lds[row*72 + 16 + l16] = f2bf(sacc[rt][1][r]*inv);
      p_lds[row*72 + 32 + l16] = f2bf(sacc[rt][2][r]*inv);
      p_lds[row*72 + 48 + l16] = f2bf(sacc[rt][3][r]*inv);
    }
  }

  const int srcA = l16 + ((lg & 1) << 5);
  const int srcB = srcA + 16;
  const bool hiSel = (lg >> 1) != 0;

  f32x4 oacc[4][2];
  #pragma unroll
  for (int rt=0;rt<4;++rt)
    #pragma unroll
    for (int ct=0;ct<2;++ct)
      oacc[rt][ct] = ZERO4;

  #pragma unroll
  for (int kt=0; kt<2; ++kt){
    s16x8 ap[4], bv2[2];
    #pragma unroll
    for (int rt=0;rt<4;++rt)
      ap[rt] = *(const s16x8*)&p_lds[(rt*16+l16)*72 + kt*32 + lg*8];
    #pragma unroll
    for (int ct=0;ct<2;++ct){
      unsigned a0x = (unsigned)__shfl((int)vpk[2*kt  ][ct].x, srcA, 64);
      unsigned a0y = (unsigned)__shfl((int)vpk[2*kt  ][ct].y, srcA, 64);
      unsigned a1x = (unsigned)__shfl((int)vpk[2*kt+1][ct].x, srcA, 64);
      unsigned a1y = (unsigned)__shfl((int)vpk[2*kt+1][ct].y, srcA, 64);
      unsigned b0x = (unsigned)__shfl((int)vpk[2*kt  ][ct].x, srcB, 64);
      unsigned b0y = (unsigned)__shfl((int)vpk[2*kt  ][ct].y, srcB, 64);
      unsigned b1x = (unsigned)__shfl((int)vpk[2*kt+1][ct].x, srcB, 64);
      unsigned b1y = (unsigned)__shfl((int)vpk[2*kt+1][ct].y, srcB, 64);
      union { s16x8 v; unsigned u[4]; } fr;
      fr.u[0] = hiSel ? a1x : a0x;
      fr.u[1] = hiSel ? a1y : a0y;
      fr.u[2] = hiSel ? b1x : b0x;
      fr.u[3] = hiSel ? b1y : b0y;
      bv2[ct] = fr.v;
    }
    #pragma unroll
    for (int rt=0;rt<4;++rt)
      #pragma unroll
      for (int ct=0;ct<2;++ct)
        oacc[rt][ct] = MFMA16(ap[rt], bv2[ct], oacc[rt][ct]);
  }

  unsigned short* o_lds = p_lds;
  #pragma unroll
  for (int rt=0;rt<4;++rt)
    #pragma unroll
    for (int ct=0;ct<2;++ct){
      const int row0 = rt*16 + lg*4;
      f32x4 vv = oacc[rt][ct];
      #pragma unroll
      for (int r=0;r<4;++r)
        o_lds[(row0+r)*40 + ct*16 + l16] = f2bf(vv[r]);
    }
  unsigned short* attb = att + (size_t)b*49*512 + h*32;
  for (int i = lane; i < 49*4; i += 64){
    const int row = i >> 2, seg = i & 3;
    *(s16x8*)&attb[(size_t)row*512 + seg*8] = *(const s16x8*)&o_lds[row*40 + seg*8];
  }
}

// ---------------- launcher -------------------------------------------------
extern "C" void kernel_launch(void* const* d_in, const int* in_sizes, int n_in,
                              void* d_out, int out_size, void* d_ws, size_t ws_size,
                              hipStream_t stream)
{
  const float* x      = (const float*)d_in[0];
  const float* qkv_w  = (const float*)d_in[1];
  const float* qkv_b  = (const float*)d_in[2];
  const float* btab   = (const float*)d_in[3];
  const float* proj_w = (const float*)d_in[4];
  const float* proj_b = (const float*)d_in[5];
  float* out = (float*)d_out;

  char* ws = (char*)d_ws;
  const size_t QKV = 154140672ULL;  // 50176*1536*2
  const size_t ATT = 51380224ULL;   // 50176*512*2 (aliases xb)
  const size_t WQ  = 1572864ULL;
  const size_t WP  = 524288ULL;
  const size_t BT  = 262144ULL;     // 16*64*64*4
  const size_t need_new = ATT + QKV + WQ + WP + BT + 8192;   // ~208 MB (proven)
  const size_t need_big = ATT + ATT + WQ + WP + BT + 8192;   // ~105 MB fallback

  if (ws_size >= need_new){
    unsigned short* attxb   = (unsigned short*)ws;            // xb, later att
    unsigned short* qkvb    = (unsigned short*)(ws + ATT);
    unsigned short* wqkv_t  = (unsigned short*)(ws + ATT + QKV);
    unsigned short* wproj_t = (unsigned short*)(ws + ATT + QKV + WQ);
    float*          bias_t  = (float*)(ws + ATT + QKV + WQ + WP);
    float*          bqkv_s  = (float*)(ws + ATT + QKV + WQ + WP + BT);

    k_prep2<<<12544 + 512, 256, 0, stream>>>(x, qkv_w, qkv_b, proj_w, btab,
                                             attxb, wqkv_t, wproj_t, bqkv_s, bias_t);
    k_qkv2<<<4704, 256, 0, stream>>>(attxb, wqkv_t, bqkv_s, qkvb);
    k_attn3<<<4096, 256, 0, stream>>>(qkvb, bias_t, attxb);   // overwrites xb
    k_proj2<<<1568, 256, 0, stream>>>(attxb, wproj_t, proj_b, out);
  } else {
    unsigned short* att     = (unsigned short*)ws;
    unsigned short* xbb     = (unsigned short*)(ws + ATT);
    unsigned short* wqkv_t  = (unsigned short*)(ws + ATT + ATT);
    unsigned short* wproj_t = (unsigned short*)(ws + ATT + ATT + WQ);
    float*          bias_t  = (float*)(ws + ATT + ATT + WQ + WP);
    float*          bqkv_s  = (float*)(ws + ATT + ATT + WQ + WP + BT);

    k_prep2<<<12544 + 512, 256, 0, stream>>>(x, qkv_w, qkv_b, proj_w, btab,
                                             xbb, wqkv_t, wproj_t, bqkv_s, bias_t);
    k_qkv_attn8<<<1024*4, 256, 0, stream>>>(xbb, wqkv_t, bqkv_s, bias_t, att);
    k_proj2<<<392*4, 256, 0, stream>>>(att, wproj_t, proj_b, out);
  }
}

// Round 14
// 228.244 us; speedup vs baseline: 1.1058x; 1.1058x over previous
//
#include <hip/hip_runtime.h>
#include <hip/hip_bf16.h>

typedef __attribute__((ext_vector_type(4))) float f32x4;
typedef __attribute__((ext_vector_type(8))) short s16x8;

#define MFMA16(a,b,c) __builtin_amdgcn_mfma_f32_16x16x32_bf16(a,b,c,0,0,0)

__device__ __forceinline__ unsigned short f2bf(float f){
  __hip_bfloat16 h = __float2bfloat16(f);
  return *reinterpret_cast<unsigned short*>(&h);
}

__device__ __forceinline__ s16x8 cvt8(f32x4 a, f32x4 b){
  s16x8 t;
  t[0]=(short)f2bf(a[0]); t[1]=(short)f2bf(a[1]);
  t[2]=(short)f2bf(a[2]); t[3]=(short)f2bf(a[3]);
  t[4]=(short)f2bf(b[0]); t[5]=(short)f2bf(b[1]);
  t[6]=(short)f2bf(b[2]); t[7]=(short)f2bf(b[3]);
  return t;
}

__device__ __forceinline__ void gload_lds16(const unsigned short* g, unsigned short* l){
  __builtin_amdgcn_global_load_lds(
      (const __attribute__((address_space(1))) unsigned int*)(const void*)g,
      (__attribute__((address_space(3))) unsigned int*)(void*)l,
      16, 0, 0);
}

// ---------------- fused x->bf16 cast + weight prep (R10-proven) ------------
__global__ void k_prep2(const float* __restrict__ x,
                        const float* __restrict__ qkv_w,   // (512,1536)
                        const float* __restrict__ qkv_b,   // (1536)
                        const float* __restrict__ proj_w,  // (512,512)
                        const float* __restrict__ btab,    // (169,16)
                        unsigned short* __restrict__ xb,      // (50176,512) bf16
                        unsigned short* __restrict__ wqkv_t,  // (1536,512) bf16
                        unsigned short* __restrict__ wproj_t, // (512,512) bf16
                        float* __restrict__ bqkv_s,           // (1536) f32
                        float* __restrict__ bias_t)           // (16,64,64) f32
{
  if (blockIdx.x < 12544){
    const int i = blockIdx.x * 256 + threadIdx.x;
    const float* p = x + (size_t)i*8;
    f32x4 v0 = *(const f32x4*)p, v1 = *(const f32x4*)(p+4);
    *(s16x8*)(xb + (size_t)i*8) = cvt8(v0, v1);
    return;
  }
  const float scale = 0.17677669529663687f; // 32^-0.5
  int tid = (blockIdx.x - 12544) * 256 + threadIdx.x;
  int np  = 512 * 256;
  for (int i = tid; i < 1536*512; i += np){
    int c = i >> 9, k = i & 511;
    float w = qkv_w[k*1536 + c];
    if (c < 512) w *= scale;
    wqkv_t[i] = f2bf(w);
  }
  for (int i = tid; i < 512*512; i += np){
    int c = i >> 9, k = i & 511;
    wproj_t[i] = f2bf(proj_w[k*512 + c]);
  }
  for (int i = tid; i < 1536; i += np){
    float bv = qkv_b[i];
    if (i < 512) bv *= scale;
    bqkv_s[i] = bv;
  }
  for (int i = tid; i < 16*64*64; i += np){
    int hh = i >> 12, rc = i & 4095, row = rc >> 6, col = rc & 63;
    float v;
    if (col >= 49)      v = -1e30f;
    else if (row >= 49) v = 0.f;
    else {
      int qy = row/7, qx = row%7, ky = col/7, kx = col%7;
      v = btab[((qy-ky+6)*13 + (qx-kx+6))*16 + hh];
    }
    bias_t[i] = v;
  }
}

// ---------------- qkv GEMM v3: 3-buffer pipeline, counted vmcnt ------------
// M=50176 (392 tiles), N=1536 (12 tiles), K=512 (16 steps). Grid 4704.
// LDS: A 3x[128][32] + B 3x[128][32] bf16 = 48 KB. Tile t -> buf t%3, staged
// 2 iters ahead. Per iter: vmcnt(4) [only tile ks's loads] + RAW s_barrier
// (no drain of in-flight prefetch) + stage(ks+2) + ds_read + 16 MFMA.
__global__ __launch_bounds__(256) void k_qkv3(
    const unsigned short* __restrict__ xb,     // (50176,512) bf16
    const unsigned short* __restrict__ wqkv_t, // (1536,512) bf16 (q pre-scaled)
    const float* __restrict__ bqkv_s,          // (1536) f32 (q pre-scaled)
    unsigned short* __restrict__ qkvb)         // (50176,1536) bf16
{
  __shared__ unsigned short lds[24576];   // A:[0,12288) x3, B:[12288,24576) x3
  const int t    = threadIdx.x;
  const int lane = t & 63;
  const int wave = t >> 6;
  const int l16  = lane & 15;
  const int lg   = lane >> 4;
  const int wr   = wave >> 1;
  const int wc   = wave & 1;
  const f32x4 ZERO4 = {0.f, 0.f, 0.f, 0.f};

  const int bid  = blockIdx.x;
  const int xcd  = bid & 7;
  const int idx  = bid >> 3;
  const int nb   = idx % 12;
  const int mgrp = idx / 12;          // 0..48
  const int mb   = xcd*49 + mgrp;     // 0..391
  const int m0   = mb * 128;
  const int n0   = nb * 128;

  const int srow = t >> 2;            // 0..63
  const int scol = (t & 3) * 8;
  const unsigned short* asrc = xb     + (size_t)(m0 + srow)*512 + scol;
  const unsigned short* bsrc = wqkv_t + (size_t)(n0 + srow)*512 + scol;

#define STAGE_Q(T, BUF) {                                                  \
    const unsigned short* a2_ = asrc + (T)*32;                             \
    const unsigned short* b2_ = bsrc + (T)*32;                             \
    gload_lds16(a2_,         lds + (BUF)*4096 + wave*512);                 \
    gload_lds16(a2_ + 32768, lds + (BUF)*4096 + 2048 + wave*512);          \
    gload_lds16(b2_,         lds + 12288 + (BUF)*4096 + wave*512);         \
    gload_lds16(b2_ + 32768, lds + 12288 + (BUF)*4096 + 2048 + wave*512);  \
  }

  // prologue: tiles 0,1 in flight (8 loads/thread)
  STAGE_Q(0, 0)
  STAGE_Q(1, 1)

  f32x4 acc[4][4];
  #pragma unroll
  for (int rt=0;rt<4;++rt)
    #pragma unroll
    for (int ct=0;ct<4;++ct)
      acc[rt][ct] = ZERO4;

  #pragma unroll
  for (int ks = 0; ks < 16; ++ks){
    // wait ONLY for tile ks's 4 loads (oldest); tile ks+1's stay in flight
    if (ks < 15) asm volatile("s_waitcnt vmcnt(4)" ::: "memory");
    else         asm volatile("s_waitcnt vmcnt(0)" ::: "memory");
    __builtin_amdgcn_s_barrier();   // raw: no compiler-forced vmcnt(0) drain
    __builtin_amdgcn_sched_barrier(0);

    // stage tile ks+2 into buf (ks+2)%3 (read in iter ks-1; safe post-barrier)
    if (ks + 2 < 16) STAGE_Q(ks + 2, (ks + 2) % 3)

    const int p = ks % 3;
    unsigned short* Ab = lds + p*4096;
    unsigned short* Bb = lds + 12288 + p*4096;
    s16x8 af[4], bf[4];
    #pragma unroll
    for (int rt=0;rt<4;++rt)
      af[rt] = *(const s16x8*)&Ab[(wr*64 + rt*16 + l16)*32 + lg*8];
    #pragma unroll
    for (int ct=0;ct<4;++ct)
      bf[ct] = *(const s16x8*)&Bb[(wc*64 + ct*16 + l16)*32 + lg*8];

    #pragma unroll
    for (int rt=0;rt<4;++rt)
      #pragma unroll
      for (int ct=0;ct<4;++ct)
        acc[rt][ct] = MFMA16(af[rt], bf[ct], acc[rt][ct]);
  }
#undef STAGE_Q

  #pragma unroll
  for (int ct=0;ct<4;++ct){
    const int col = n0 + wc*64 + ct*16 + l16;
    const float bv = bqkv_s[col];
    #pragma unroll
    for (int rt=0;rt<4;++rt){
      const int row = m0 + wr*64 + rt*16 + lg*4;
      #pragma unroll
      for (int r=0;r<4;++r)
        qkvb[(size_t)(row+r)*1536 + col] = f2bf(acc[rt][ct][r] + bv);
    }
  }
}

// ---------------- attention kernel (R12-proven k_attn2) --------------------
__global__ __launch_bounds__(256, 3) void k_attn2(
    const unsigned short* __restrict__ qkvb,  // (50176,1536) bf16
    const float* __restrict__ bias_t,         // (16,64,64) f32, mask folded
    unsigned short* __restrict__ att)         // (1024,49,512) bf16
{
  __shared__ unsigned short lds[4*6656];
  const int lane = threadIdx.x & 63;
  const int wave = threadIdx.x >> 6;
  const int bid  = blockIdx.x;
  const int xcd  = bid & 7;
  const int g    = (bid >> 3) & 3;
  const int wblk = bid >> 5;
  const int b    = xcd + (wblk << 3);
  const int h    = (g << 2) | wave;
  const int l16  = lane & 15;
  const int lg   = lane >> 4;
  const f32x4 ZERO4 = {0.f, 0.f, 0.f, 0.f};

  unsigned short* p_lds = lds + wave*6656;   // [64][72]
  unsigned short* vT    = p_lds + 4608;      // [64][32] (token, d)
  const size_t wbase = (size_t)b * 49;

  for (int i = lane; i < 15*32; i += 64) vT[49*32 + i] = 0;

  // stage V into LDS (lands under QK^T + softmax)
  {
    const int tokb = lane >> 2;
    const int sc   = (lane & 3) * 8;
    #pragma unroll
    for (int i=0;i<4;++i){
      const int tok = i*16 + tokb;
      if (tok < 49)
        gload_lds16(qkvb + (wbase + tok)*1536 + 1024 + h*32 + sc,
                    vT + i*512);
    }
  }

  s16x8 aq[4], bk[4];
  #pragma unroll
  for (int rt=0;rt<4;++rt){
    const int n = rt*16 + l16;
    s16x8 z = {0,0,0,0,0,0,0,0};
    aq[rt] = z; bk[rt] = z;
    if (n < 49){
      const unsigned short* qp = qkvb + (wbase + n)*1536 + h*32 + lg*8;
      aq[rt] = *(const s16x8*)qp;
      bk[rt] = *(const s16x8*)(qp + 512);
    }
  }

  f32x4 sacc[4][4];
  #pragma unroll
  for (int rt=0;rt<4;++rt)
    #pragma unroll
    for (int ct=0;ct<4;++ct)
      sacc[rt][ct] = MFMA16(aq[rt], bk[ct], ZERO4);

  const float* biash = bias_t + (h << 12);
  float pm[4][4];
  #pragma unroll
  for (int rt=0;rt<4;++rt){
    #pragma unroll
    for (int r=0;r<4;++r){
      const int row = rt*16 + lg*4 + r;
      const float* brow = biash + (row << 6) + l16;
      float s0 = sacc[rt][0][r] + brow[0];
      float s1 = sacc[rt][1][r] + brow[16];
      float s2 = sacc[rt][2][r] + brow[32];
      float s3 = sacc[rt][3][r] + brow[48];
      sacc[rt][0][r]=s0; sacc[rt][1][r]=s1; sacc[rt][2][r]=s2; sacc[rt][3][r]=s3;
      pm[rt][r] = fmaxf(fmaxf(s0,s1), fmaxf(s2,s3));
    }
  }
  #pragma unroll
  for (int d=1; d<16; d<<=1)
    #pragma unroll
    for (int rt=0;rt<4;++rt)
      #pragma unroll
      for (int r=0;r<4;++r)
        pm[rt][r] = fmaxf(pm[rt][r], __shfl_xor(pm[rt][r], d));

  float ps[4][4];
  #pragma unroll
  for (int rt=0;rt<4;++rt){
    #pragma unroll
    for (int r=0;r<4;++r){
      const float m = pm[rt][r];
      float e0 = __expf(sacc[rt][0][r]-m), e1 = __expf(sacc[rt][1][r]-m);
      float e2 = __expf(sacc[rt][2][r]-m), e3 = __expf(sacc[rt][3][r]-m);
      sacc[rt][0][r]=e0; sacc[rt][1][r]=e1; sacc[rt][2][r]=e2; sacc[rt][3][r]=e3;
      ps[rt][r] = e0+e1+e2+e3;
    }
  }
  #pragma unroll
  for (int d=1; d<16; d<<=1)
    #pragma unroll
    for (int rt=0;rt<4;++rt)
      #pragma unroll
      for (int r=0;r<4;++r)
        ps[rt][r] += __shfl_xor(ps[rt][r], d);

  #pragma unroll
  for (int rt=0;rt<4;++rt){
    #pragma unroll
    for (int r=0;r<4;++r){
      const int row = rt*16 + lg*4 + r;
      const float inv = 1.f / ps[rt][r];
      p_lds[row*72 +      l16] = f2bf(sacc[rt][0][r]*inv);
      p_lds[row*72 + 16 + l16] = f2bf(sacc[rt][1][r]*inv);
      p_lds[row*72 + 32 + l16] = f2bf(sacc[rt][2][r]*inv);
      p_lds[row*72 + 48 + l16] = f2bf(sacc[rt][3][r]*inv);
    }
  }

  asm volatile("s_waitcnt vmcnt(0) lgkmcnt(0)" ::: "memory");
  __builtin_amdgcn_sched_barrier(0);

  f32x4 oacc[4][2];
  #pragma unroll
  for (int rt=0;rt<4;++rt)
    #pragma unroll
    for (int ct=0;ct<2;++ct)
      oacc[rt][ct] = ZERO4;

  #pragma unroll
  for (int kt=0; kt<2; ++kt){
    s16x8 ap[4], bv2[2];
    #pragma unroll
    for (int rt=0;rt<4;++rt)
      ap[rt] = *(const s16x8*)&p_lds[(rt*16+l16)*72 + kt*32 + lg*8];
    #pragma unroll
    for (int ct=0;ct<2;++ct){
      s16x8 fr;
      #pragma unroll
      for (int j=0;j<8;++j)
        fr[j] = (short)vT[(kt*32 + lg*8 + j)*32 + ct*16 + l16];
      bv2[ct] = fr;
    }
    #pragma unroll
    for (int rt=0;rt<4;++rt)
      #pragma unroll
      for (int ct=0;ct<2;++ct)
        oacc[rt][ct] = MFMA16(ap[rt], bv2[ct], oacc[rt][ct]);
  }

  unsigned short* o_lds = p_lds;  // [64][40]
  #pragma unroll
  for (int rt=0;rt<4;++rt)
    #pragma unroll
    for (int ct=0;ct<2;++ct){
      const int row0 = rt*16 + lg*4;
      f32x4 vv = oacc[rt][ct];
      #pragma unroll
      for (int r=0;r<4;++r)
        o_lds[(row0+r)*40 + ct*16 + l16] = f2bf(vv[r]);
    }
  unsigned short* attb = att + (size_t)b*49*512 + h*32;
  for (int i = lane; i < 49*4; i += 64){
    const int row = i >> 2, seg = i & 3;
    *(s16x8*)&attb[(size_t)row*512 + seg*8] = *(const s16x8*)&o_lds[row*40 + seg*8];
  }
}

// ---------------- proj GEMM v3: 3-buffer pipeline, counted vmcnt -----------
__global__ __launch_bounds__(256) void k_proj3(
    const unsigned short* __restrict__ att,
    const unsigned short* __restrict__ wproj_t,
    const float* __restrict__ proj_b,
    float* __restrict__ out)
{
  __shared__ unsigned short lds[24576];
  const int t    = threadIdx.x;
  const int lane = t & 63;
  const int wave = t >> 6;
  const int l16  = lane & 15;
  const int lg   = lane >> 4;
  const int wr   = wave >> 1;
  const int wc   = wave & 1;
  const f32x4 ZERO4 = {0.f, 0.f, 0.f, 0.f};

  const int bid  = blockIdx.x;
  const int xcd  = bid & 7;
  const int idx  = bid >> 3;
  const int nb   = idx & 3;
  const int mgrp = idx >> 2;
  const int mb   = xcd*49 + mgrp;
  const int m0   = mb * 128;
  const int n0   = nb * 128;

  const int srow = t >> 2;
  const int scol = (t & 3) * 8;
  const unsigned short* asrc = att     + (size_t)(m0 + srow)*512 + scol;
  const unsigned short* bsrc = wproj_t + (size_t)(n0 + srow)*512 + scol;

#define STAGE_P(T, BUF) {                                                  \
    const unsigned short* a2_ = asrc + (T)*32;                             \
    const unsigned short* b2_ = bsrc + (T)*32;                             \
    gload_lds16(a2_,         lds + (BUF)*4096 + wave*512);                 \
    gload_lds16(a2_ + 32768, lds + (BUF)*4096 + 2048 + wave*512);          \
    gload_lds16(b2_,         lds + 12288 + (BUF)*4096 + wave*512);         \
    gload_lds16(b2_ + 32768, lds + 12288 + (BUF)*4096 + 2048 + wave*512);  \
  }

  STAGE_P(0, 0)
  STAGE_P(1, 1)

  f32x4 acc[4][4];
  #pragma unroll
  for (int rt=0;rt<4;++rt)
    #pragma unroll
    for (int ct=0;ct<4;++ct)
      acc[rt][ct] = ZERO4;

  #pragma unroll
  for (int ks = 0; ks < 16; ++ks){
    if (ks < 15) asm volatile("s_waitcnt vmcnt(4)" ::: "memory");
    else         asm volatile("s_waitcnt vmcnt(0)" ::: "memory");
    __builtin_amdgcn_s_barrier();
    __builtin_amdgcn_sched_barrier(0);

    if (ks + 2 < 16) STAGE_P(ks + 2, (ks + 2) % 3)

    const int p = ks % 3;
    unsigned short* Ab = lds + p*4096;
    unsigned short* Bb = lds + 12288 + p*4096;
    s16x8 af[4], bf[4];
    #pragma unroll
    for (int rt=0;rt<4;++rt)
      af[rt] = *(const s16x8*)&Ab[(wr*64 + rt*16 + l16)*32 + lg*8];
    #pragma unroll
    for (int ct=0;ct<4;++ct)
      bf[ct] = *(const s16x8*)&Bb[(wc*64 + ct*16 + l16)*32 + lg*8];

    #pragma unroll
    for (int rt=0;rt<4;++rt)
      #pragma unroll
      for (int ct=0;ct<4;++ct)
        acc[rt][ct] = MFMA16(af[rt], bf[ct], acc[rt][ct]);
  }
#undef STAGE_P

  #pragma unroll
  for (int ct=0;ct<4;++ct){
    const int col = n0 + wc*64 + ct*16 + l16;
    const float bv = proj_b[col];
    #pragma unroll
    for (int rt=0;rt<4;++rt){
      const int row = m0 + wr*64 + rt*16 + lg*4;
      #pragma unroll
      for (int r=0;r<4;++r)
        out[(size_t)(row+r)*512 + col] = acc[rt][ct][r] + bv;
    }
  }
}

// ================= R10 fused-attn kernel (fallback tier) ===================
__global__ __launch_bounds__(256, 3) void k_qkv_attn8(
    const unsigned short* __restrict__ xb,
    const unsigned short* __restrict__ wqkv_t,
    const float* __restrict__ bqkv_s,
    const float* __restrict__ bias_t,
    unsigned short* __restrict__ att)
{
  __shared__ unsigned short lds[4*5120 + 2*2048];
  const int lane = threadIdx.x & 63;
  const int wave = threadIdx.x >> 6;
  const int bid  = blockIdx.x;
  const int xcd  = bid & 7;
  const int g    = (bid >> 3) & 3;
  const int wblk = bid >> 5;
  const int b    = xcd + (wblk << 3);
  const int h    = (g << 2) | wave;
  const int l16  = lane & 15;
  const int lg   = lane >> 4;
  const f32x4 ZERO4 = {0.f, 0.f, 0.f, 0.f};

  unsigned short* q_lds  = lds + wave*5120;
  unsigned short* k_lds  = q_lds + 2560;
  unsigned short* p_lds  = q_lds;
  unsigned short* xstage = lds + 4*5120;

  for (int i = threadIdx.x; i < 2*15*32; i += 256){
    int bf = i / 480, rem = i % 480;
    xstage[bf*2048 + (49 + rem/32)*32 + (rem & 31)] = 0;
  }

  const unsigned short* xwin = xb + (size_t)b*49*512;
  const int srow = wave*16 + (lane>>2);
  const int cbase = h * 32;
  const unsigned short* xsrc = xwin + (size_t)srow*512 + (lane&3)*8;
  const unsigned short* bbase = wqkv_t + (size_t)(cbase + l16)*512 + lg*8;

  __syncthreads();
  if (srow < 49) gload_lds16(xsrc, xstage + wave*512);
  __syncthreads();

  f32x4 acc[3][4][2];
  #pragma unroll
  for (int a=0;a<3;++a)
    #pragma unroll
    for (int rt=0;rt<4;++rt)
      #pragma unroll
      for (int ct=0;ct<2;++ct)
        acc[a][rt][ct] = ZERO4;

  #pragma unroll 2
  for (int ks = 0; ks < 16; ++ks){
    const int p = ks & 1;
    s16x8 bfrag[6];
    #pragma unroll
    for (int wq=0; wq<3; ++wq)
      #pragma unroll
      for (int ct=0; ct<2; ++ct)
        bfrag[wq*2+ct] = *(const s16x8*)(bbase + wq*262144 + ct*8192 + ks*32);

    if (ks < 15 && srow < 49)
      gload_lds16(xsrc + (ks+1)*32, xstage + ((ks+1)&1)*2048 + wave*512);

    s16x8 afrag[4];
    #pragma unroll
    for (int rt=0; rt<4; ++rt)
      afrag[rt] = *(const s16x8*)&xstage[p*2048 + (rt*16 + l16)*32 + lg*8];

    #pragma unroll
    for (int wq=0;wq<3;++wq)
      #pragma unroll
      for (int rt=0;rt<4;++rt)
        #pragma unroll
        for (int ct=0;ct<2;++ct)
          acc[wq][rt][ct] = MFMA16(afrag[rt], bfrag[wq*2+ct], acc[wq][rt][ct]);

    __syncthreads();
  }

  uint2 vpk[4][2];
  #pragma unroll
  for (int wq=0; wq<3; ++wq){
    #pragma unroll
    for (int ct=0; ct<2; ++ct){
      const int c = wq*512 + cbase + ct*16 + l16;
      const float bv = bqkv_s[c];
      #pragma unroll
      for (int rt=0; rt<4; ++rt){
        f32x4 vv = acc[wq][rt][ct];
        const int row0 = rt*16 + lg*4;
        if (wq == 0){
          #pragma unroll
          for (int r=0;r<4;++r) q_lds[(row0+r)*40 + ct*16 + l16] = f2bf(vv[r]+bv);
        } else if (wq == 1){
          #pragma unroll
          for (int r=0;r<4;++r) k_lds[(row0+r)*40 + ct*16 + l16] = f2bf(vv[r]+bv);
        } else {
          uint2 pk;
          pk.x = (unsigned)f2bf(vv[0]+bv) | ((unsigned)f2bf(vv[1]+bv) << 16);
          pk.y = (unsigned)f2bf(vv[2]+bv) | ((unsigned)f2bf(vv[3]+bv) << 16);
          vpk[rt][ct] = pk;
        }
      }
    }
  }

  s16x8 aq[4], bk[4];
  #pragma unroll
  for (int t=0;t<4;++t){
    aq[t] = *(const s16x8*)&q_lds[(t*16+l16)*40 + lg*8];
    bk[t] = *(const s16x8*)&k_lds[(t*16+l16)*40 + lg*8];
  }
  f32x4 sacc[4][4];
  #pragma unroll
  for (int rt=0;rt<4;++rt)
    #pragma unroll
    for (int ct=0;ct<4;++ct)
      sacc[rt][ct] = MFMA16(aq[rt], bk[ct], ZERO4);

  const float* biash = bias_t + (h << 12);
  float pm[4][4];
  #pragma unroll
  for (int rt=0;rt<4;++rt){
    #pragma unroll
    for (int r=0;r<4;++r){
      const int row = rt*16 + lg*4 + r;
      const float* brow = biash + (row << 6) + l16;
      float s0 = sacc[rt][0][r] + brow[0];
      float s1 = sacc[rt][1][r] + brow[16];
      float s2 = sacc[rt][2][r] + brow[32];
      float s3 = sacc[rt][3][r] + brow[48];
      sacc[rt][0][r]=s0; sacc[rt][1][r]=s1; sacc[rt][2][r]=s2; sacc[rt][3][r]=s3;
      pm[rt][r] = fmaxf(fmaxf(s0,s1), fmaxf(s2,s3));
    }
  }
  #pragma unroll
  for (int d=1; d<16; d<<=1)
    #pragma unroll
    for (int rt=0;rt<4;++rt)
      #pragma unroll
      for (int r=0;r<4;++r)
        pm[rt][r] = fmaxf(pm[rt][r], __shfl_xor(pm[rt][r], d));

  float ps[4][4];
  #pragma unroll
  for (int rt=0;rt<4;++rt){
    #pragma unroll
    for (int r=0;r<4;++r){
      const float m = pm[rt][r];
      float e0 = __expf(sacc[rt][0][r]-m), e1 = __expf(sacc[rt][1][r]-m);
      float e2 = __expf(sacc[rt][2][r]-m), e3 = __expf(sacc[rt][3][r]-m);
      sacc[rt][0][r]=e0; sacc[rt][1][r]=e1; sacc[rt][2][r]=e2; sacc[rt][3][r]=e3;
      ps[rt][r] = e0+e1+e2+e3;
    }
  }
  #pragma unroll
  for (int d=1; d<16; d<<=1)
    #pragma unroll
    for (int rt=0;rt<4;++rt)
      #pragma unroll
      for (int r=0;r<4;++r)
        ps[rt][r] += __shfl_xor(ps[rt][r], d);

  #pragma unroll
  for (int rt=0;rt<4;++rt){
    #pragma unroll
    for (int r=0;r<4;++r){
      const int row = rt*16 + lg*4 + r;
      const float inv = 1.f / ps[rt][r];
      p_lds[row*72 +      l16] = f2bf(sacc[rt][0][r]*inv);
      p_lds[row*72 + 16 + l16] = f2bf(sacc[rt][1][r]*inv);
      p_lds[row*72 + 32 + l16] = f2bf(sacc[rt][2][r]*inv);
      p_lds[row*72 + 48 + l16] = f2bf(sacc[rt][3][r]*inv);
    }
  }

  const int srcA = l16 + ((lg & 1) << 5);
  const int srcB = srcA + 16;
  const bool hiSel = (lg >> 1) != 0;

  f32x4 oacc[4][2];
  #pragma unroll
  for (int rt=0;rt<4;++rt)
    #pragma unroll
    for (int ct=0;ct<2;++ct)
      oacc[rt][ct] = ZERO4;

  #pragma unroll
  for (int kt=0; kt<2; ++kt){
    s16x8 ap[4], bv2[2];
    #pragma unroll
    for (int rt=0;rt<4;++rt)
      ap[rt] = *(const s16x8*)&p_lds[(rt*16+l16)*72 + kt*32 + lg*8];
    #pragma unroll
    for (int ct=0;ct<2;++ct){
      unsigned a0x = (unsigned)__shfl((int)vpk[2*kt  ][ct].x, srcA, 64);
      unsigned a0y = (unsigned)__shfl((int)vpk[2*kt  ][ct].y, srcA, 64);
      unsigned a1x = (unsigned)__shfl((int)vpk[2*kt+1][ct].x, srcA, 64);
      unsigned a1y = (unsigned)__shfl((int)vpk[2*kt+1][ct].y, srcA, 64);
      unsigned b0x = (unsigned)__shfl((int)vpk[2*kt  ][ct].x, srcB, 64);
      unsigned b0y = (unsigned)__shfl((int)vpk[2*kt  ][ct].y, srcB, 64);
      unsigned b1x = (unsigned)__shfl((int)vpk[2*kt+1][ct].x, srcB, 64);
      unsigned b1y = (unsigned)__shfl((int)vpk[2*kt+1][ct].y, srcB, 64);
      union { s16x8 v; unsigned u[4]; } fr;
      fr.u[0] = hiSel ? a1x : a0x;
      fr.u[1] = hiSel ? a1y : a0y;
      fr.u[2] = hiSel ? b1x : b0x;
      fr.u[3] = hiSel ? b1y : b0y;
      bv2[ct] = fr.v;
    }
    #pragma unroll
    for (int rt=0;rt<4;++rt)
      #pragma unroll
      for (int ct=0;ct<2;++ct)
        oacc[rt][ct] = MFMA16(ap[rt], bv2[ct], oacc[rt][ct]);
  }

  unsigned short* o_lds = p_lds;
  #pragma unroll
  for (int rt=0;rt<4;++rt)
    #pragma unroll
    for (int ct=0;ct<2;++ct){
      const int row0 = rt*16 + lg*4;
      f32x4 vv = oacc[rt][ct];
      #pragma unroll
      for (int r=0;r<4;++r)
        o_lds[(row0+r)*40 + ct*16 + l16] = f2bf(vv[r]);
    }
  unsigned short* attb = att + (size_t)b*49*512 + h*32;
  for (int i = lane; i < 49*4; i += 64){
    const int row = i >> 2, seg = i & 3;
    *(s16x8*)&attb[(size_t)row*512 + seg*8] = *(const s16x8*)&o_lds[row*40 + seg*8];
  }
}

// ---------------- launcher -------------------------------------------------
extern "C" void kernel_launch(void* const* d_in, const int* in_sizes, int n_in,
                              void* d_out, int out_size, void* d_ws, size_t ws_size,
                              hipStream_t stream)
{
  const float* x      = (const float*)d_in[0];
  const float* qkv_w  = (const float*)d_in[1];
  const float* qkv_b  = (const float*)d_in[2];
  const float* btab   = (const float*)d_in[3];
  const float* proj_w = (const float*)d_in[4];
  const float* proj_b = (const float*)d_in[5];
  float* out = (float*)d_out;

  char* ws = (char*)d_ws;
  const size_t QKV = 154140672ULL;  // 50176*1536*2
  const size_t ATT = 51380224ULL;   // 50176*512*2 (aliases xb)
  const size_t WQ  = 1572864ULL;
  const size_t WP  = 524288ULL;
  const size_t BT  = 262144ULL;     // 16*64*64*4
  const size_t need_new = ATT + QKV + WQ + WP + BT + 8192;   // ~208 MB (proven)
  const size_t need_big = ATT + ATT + WQ + WP + BT + 8192;   // ~105 MB fallback

  if (ws_size >= need_new){
    unsigned short* attxb   = (unsigned short*)ws;            // xb, later att
    unsigned short* qkvb    = (unsigned short*)(ws + ATT);
    unsigned short* wqkv_t  = (unsigned short*)(ws + ATT + QKV);
    unsigned short* wproj_t = (unsigned short*)(ws + ATT + QKV + WQ);
    float*          bias_t  = (float*)(ws + ATT + QKV + WQ + WP);
    float*          bqkv_s  = (float*)(ws + ATT + QKV + WQ + WP + BT);

    k_prep2<<<12544 + 512, 256, 0, stream>>>(x, qkv_w, qkv_b, proj_w, btab,
                                             attxb, wqkv_t, wproj_t, bqkv_s, bias_t);
    k_qkv3<<<4704, 256, 0, stream>>>(attxb, wqkv_t, bqkv_s, qkvb);
    k_attn2<<<4096, 256, 0, stream>>>(qkvb, bias_t, attxb);   // overwrites xb
    k_proj3<<<1568, 256, 0, stream>>>(attxb, wproj_t, proj_b, out);
  } else {
    unsigned short* att     = (unsigned short*)ws;
    unsigned short* xbb     = (unsigned short*)(ws + ATT);
    unsigned short* wqkv_t  = (unsigned short*)(ws + ATT + ATT);
    unsigned short* wproj_t = (unsigned short*)(ws + ATT + ATT + WQ);
    float*          bias_t  = (float*)(ws + ATT + ATT + WQ + WP);
    float*          bqkv_s  = (float*)(ws + ATT + ATT + WQ + WP + BT);

    k_prep2<<<12544 + 512, 256, 0, stream>>>(x, qkv_w, qkv_b, proj_w, btab,
                                             xbb, wqkv_t, wproj_t, bqkv_s, bias_t);
    k_qkv_attn8<<<1024*4, 256, 0, stream>>>(xbb, wqkv_t, bqkv_s, bias_t, att);
    k_proj3<<<392*4, 256, 0, stream>>>(att, wproj_t, proj_b, out);
  }
}